// Round 1
// baseline (62.882 us; speedup 1.0000x reference)
//
#include <hip/hip_runtime.h>

// Output = abs(column 63 after both transforms). Only W1 row 63 and the
// combinations P = W2r+W2i, Q = W2r-W2i are needed. Memory-bound: streams
// all of x (256 MiB) once.

static constexpr int NB_PER_WAVE = 2;   // batches per wave; block = 4 waves

__global__ __launch_bounds__(256, 4)
void cnet_kernel(const float* __restrict__ x,
                 const float* __restrict__ W1r,
                 const float* __restrict__ W1i,
                 const float* __restrict__ W2r,
                 const float* __restrict__ W2i,
                 float* __restrict__ out) {
    // Transposed, padded P/Q for conflict-free phase-B reads (lane = m).
    __shared__ float Pt[64 * 65];
    __shared__ float Qt[64 * 65];
    __shared__ float YrW[4][64];
    __shared__ float YiW[4][64];

    const int tid  = threadIdx.x;
    const int w    = tid >> 6;    // wave id 0..3
    const int lane = tid & 63;
    const int h    = lane & 31;   // column-pair index within a row
    const int s    = lane >> 5;   // which row of the pair this half-wave owns

    // Stage P/Q transposed: Pt[n][m] = W2r[m,n] + W2i[m,n], Qt = diff.
    for (int idx = tid; idx < 4096; idx += 256) {
        const int m = idx >> 6;
        const int n = idx & 63;
        const float wr = W2r[idx];
        const float wi = W2i[idx];
        Pt[n * 65 + m] = wr + wi;
        Qt[n * 65 + m] = wr - wi;
    }

    // W1 row 63 coefficients for columns 2h, 2h+1 (per-lane registers).
    const float2 Av = ((const float2*)(W1r + 63 * 64))[h];
    const float2 Bv = ((const float2*)(W1i + 63 * 64))[h];

    __syncthreads();

    for (int g = 0; g < NB_PER_WAVE; ++g) {
        const int b = (blockIdx.x * 4 + w) * NB_PER_WAVE + g;
        const float4* xp = (const float4*)x + (size_t)b * 2048;  // 2048 float4 per batch

        // ---- Phase A: Y[n] = (post-transform-1) column 63 of batch b ----
        // Two rows per pass: lanes 0..31 -> row 2*rp, lanes 32..63 -> row 2*rp+1.
        #pragma unroll 8
        for (int rp = 0; rp < 32; ++rp) {
            const int n = rp * 2 + s;
            const float4 v = xp[n * 32 + h];  // (r_{2h}, i_{2h}, r_{2h+1}, i_{2h+1})
            float pr = v.x * Av.x - v.y * Bv.x + v.z * Av.y - v.w * Bv.y;
            float pi = v.y * Av.x + v.x * Bv.x + v.w * Av.y + v.z * Bv.y;
            #pragma unroll
            for (int msk = 1; msk < 32; msk <<= 1) {  // reduce within 32-lane halves
                pr += __shfl_xor(pr, msk);
                pi += __shfl_xor(pi, msk);
            }
            if (rp == 0) {
                // Row 0 is NOT transformed by phase 1: pass through x[b,0,63,:].
                const float r0r = __shfl(v.z, 31);  // lane 31 holds c=62,63
                const float r0i = __shfl(v.w, 31);
                if (lane == 0)  { YrW[w][0] = r0r; YiW[w][0] = r0i; }
                if (lane == 32) { YrW[w][1] = pr;  YiW[w][1] = pi; }
            } else if (h == 0) {
                YrW[w][n] = pr;
                YiW[w][n] = pi;
            }
        }

        // ---- Phase B: out[b,m] = | sum_n Yr[n]*P[m,n] + Yi[n]*Q[m,n] | ----
        float acc = 0.f;
        #pragma unroll 8
        for (int n = 0; n < 64; ++n) {
            acc += YrW[w][n] * Pt[n * 65 + lane] + YiW[w][n] * Qt[n * 65 + lane];
        }
        out[(size_t)b * 64 + lane] = fabsf(acc);
    }
}

extern "C" void kernel_launch(void* const* d_in, const int* in_sizes, int n_in,
                              void* d_out, int out_size, void* d_ws, size_t ws_size,
                              hipStream_t stream) {
    const float* x   = (const float*)d_in[0];
    const float* W1r = (const float*)d_in[1];
    const float* W1i = (const float*)d_in[2];
    const float* W2r = (const float*)d_in[3];
    const float* W2i = (const float*)d_in[4];
    float* o = (float*)d_out;

    const int B = in_sizes[0] / (64 * 64 * 2);          // 8192 batches
    const int nblocks = B / (4 * NB_PER_WAVE);          // 1024 blocks
    hipLaunchKernelGGL(cnet_kernel, dim3(nblocks), dim3(256), 0, stream,
                       x, W1r, W1i, W2r, W2i, o);
}

// Round 2
// 49.687 us; speedup vs baseline: 1.2656x; 1.2656x over previous
//
#include <hip/hip_runtime.h>
#include <hip/hip_fp16.h>

// Output = abs(column 63 after both transforms). Only W1 row 63 and
// P = W2r+W2i, Q = W2r-W2i are needed. Memory-bound: streams x (256 MiB) once.
//
// Phase A: Y[b,n] = sum_c x[b,n,c] * conj-weighted W1[63,c]  (row 0 passthrough)
//   lane layout: 16 lanes per row (4 complexes each), 4 rows per wave-iter,
//   4-step butterfly reduce (was 5-step over 32 lanes -> 2.5x fewer shuffles).
// Phase B: out[b,m] = | sum_n Yr[n]*P[m,n] + Yi[n]*Q[m,n] |
//   P,Q packed as half2 in LDS (18.7 KiB total -> 8 blocks/CU, 32 waves/CU).

__global__ __launch_bounds__(256, 8)
void cnet_kernel(const float* __restrict__ x,
                 const float* __restrict__ W1r,
                 const float* __restrict__ W1i,
                 const float* __restrict__ W2r,
                 const float* __restrict__ W2i,
                 float* __restrict__ out) {
    __shared__ __half2 PQt[64 * 65];   // [n][m] = (P[m,n], Q[m,n]); stride 65 dwords
    __shared__ float2  YW[4][64];      // per-wave phase-A result (col 63 after T1)

    const int tid  = threadIdx.x;
    const int w    = tid >> 6;    // wave id 0..3
    const int lane = tid & 63;
    const int lg   = lane >> 4;   // row within quad (0..3)
    const int li   = lane & 15;   // position within row: complexes 4li..4li+3

    // Stage P/Q packed fp16, transposed: PQt[n][m]. Coalesced W2 reads,
    // conflict-free writes (consecutive tid -> consecutive dwords).
    for (int idx = tid; idx < 4096; idx += 256) {
        const int m = idx >> 6;
        const int n = idx & 63;
        const float wr = W2r[idx];
        const float wi = W2i[idx];
        PQt[n * 65 + m] = __halves2half2(__float2half_rn(wr + wi),
                                         __float2half_rn(wr - wi));
    }

    // W1 row 63 coefficients for this lane's 4 columns (4li..4li+3).
    const float4 A0 = ((const float4*)(W1r + 63 * 64))[li];
    const float4 B0 = ((const float4*)(W1i + 63 * 64))[li];

    __syncthreads();

    const int b = blockIdx.x * 4 + w;                       // one batch per wave
    const float4* xp = (const float4*)x + (size_t)b * 2048; // 2048 float4/batch

    // ---- Phase A ----
    #pragma unroll 4
    for (int q = 0; q < 16; ++q) {
        // Lane loads 32B contiguous: complexes 4*lane .. 4*lane+3 of the batch,
        // i.e. row lg (= lane/16) of quad q, columns 4li..4li+3.
        const float4 u = xp[q * 128 + 2 * lane];
        const float4 v = xp[q * 128 + 2 * lane + 1];
        float pr = u.x*A0.x - u.y*B0.x + u.z*A0.y - u.w*B0.y
                 + v.x*A0.z - v.y*B0.z + v.z*A0.w - v.w*B0.w;
        float pi = u.y*A0.x + u.x*B0.x + u.w*A0.y + u.z*B0.y
                 + v.y*A0.z + v.x*B0.z + v.w*A0.w + v.z*B0.w;
        #pragma unroll
        for (int msk = 1; msk < 16; msk <<= 1) {   // reduce within 16-lane groups
            pr += __shfl_xor(pr, msk);
            pi += __shfl_xor(pi, msk);
        }
        const int n = q * 4 + lg;
        if (q == 0) {
            // Row 0 is NOT transformed: passthrough x[b,0,63,:] (lane 15's v.z/v.w).
            if (lane == 15) YW[w][0] = make_float2(v.z, v.w);
            if (li == 0 && lg != 0) YW[w][n] = make_float2(pr, pi);
        } else if (li == 0) {
            YW[w][n] = make_float2(pr, pi);
        }
    }
    // YW written and read by the same wave only -> no barrier needed
    // (compiler orders same-array LDS ops via lgkmcnt).

    // ---- Phase B: lane = output index m ----
    float acc = 0.f;
    #pragma unroll 8
    for (int n = 0; n < 64; ++n) {
        const float2  y  = YW[w][n];            // broadcast read (free)
        const __half2 pq = PQt[n * 65 + lane];  // conflict-free b32 read
        acc += y.x * __low2float(pq) + y.y * __high2float(pq);
    }
    out[(size_t)b * 64 + lane] = fabsf(acc);
}

extern "C" void kernel_launch(void* const* d_in, const int* in_sizes, int n_in,
                              void* d_out, int out_size, void* d_ws, size_t ws_size,
                              hipStream_t stream) {
    const float* x   = (const float*)d_in[0];
    const float* W1r = (const float*)d_in[1];
    const float* W1i = (const float*)d_in[2];
    const float* W2r = (const float*)d_in[3];
    const float* W2i = (const float*)d_in[4];
    float* o = (float*)d_out;

    const int B = in_sizes[0] / (64 * 64 * 2);   // 8192 batches
    const int nblocks = B / 4;                   // 1 batch per wave, 4 waves/block
    hipLaunchKernelGGL(cnet_kernel, dim3(nblocks), dim3(256), 0, stream,
                       x, W1r, W1i, W2r, W2i, o);
}